// Round 7
// baseline (550.177 us; speedup 1.0000x reference)
//
#include <hip/hip_runtime.h>

#define ZD 64
#define RD 128
#define HIDDEN 512
#define NSTEP 100
#define OUT_PITCH 6464              // 101*64
#define DT_F 0.01f
#define ROWS 32

static const size_t LW_OFF = 52953088ull;   // 8192*101*64
static const size_t NG_OFF = 52961280ull;   // + 8192

typedef __attribute__((ext_vector_type(4))) float  f32x4;
typedef __attribute__((ext_vector_type(8))) __bf16 bf16x8;
typedef __attribute__((ext_vector_type(4))) short  s16x4;
typedef __attribute__((ext_vector_type(8))) short  s16x8;

__device__ __forceinline__ short f2bs(float f) {
    return __builtin_bit_cast(short, (__bf16)f);
}
__device__ __forceinline__ float tanh_fast(float x) {
    float e = __builtin_amdgcn_exp2f(x * 2.88539008177793f);
    float r = __builtin_amdgcn_rcpf(e + 1.0f);
    return fmaf(-2.0f, r, 1.0f);
}

// ---------------------------------------------------------------------------
// sim_kernel: persistent scan, wave-specialized. 256 blocks x 1024 threads
// (16 waves), 32 rows/block, 1 block/CU.
//   S-waves (0-7): role (zt=w&3, mt=w>>2). Hold x-state + w2f[16] (full K).
//     GEMM2 + update + x_t/Xb writes all in ONE phase (no partial-sum LDS).
//   M-waves (8-15): GEMM1 (4 n-tiles x 2 m-tiles) + tanh -> Hs.
// 2 barriers/step. W[16]/P[8] arrays shared between roles so register
// allocation is the max of the roles, not the union (~120 combined).
// ---------------------------------------------------------------------------
__global__ __launch_bounds__(1024, 1)
void sim_kernel(
    const float* __restrict__ r, const float* __restrict__ noises,
    const float* __restrict__ x0, const float* __restrict__ W1,
    const float* __restrict__ b1, const float* __restrict__ W2,
    const float* __restrict__ b2, const float* __restrict__ bmax,
    const float* __restrict__ bmin, const float* __restrict__ mu,
    float* __restrict__ out)
{
    __shared__ unsigned short Xb[ROWS * 64];          // 4096 B
    __shared__ unsigned short Hs[ROWS * HIDDEN];      // 32768 B
    __shared__ float w1ts[HIDDEN];                    // 2048 B
    __shared__ float tT[NSTEP], tG[NSTEP], tSd[NSTEP], tCd[NSTEP], tCs[NSTEP]; // 2000 B
    __shared__ float lwP[4][ROWS];                    // 512 B

    const int tid  = threadIdx.x;
    const int lane = tid & 63;
    const int wave = tid >> 6;       // 0..15
    const int g4   = lane >> 4;      // 0..3
    const int l16  = lane & 15;
    const int row0 = blockIdx.x * ROWS;

    // ---- step tables ----
    if (tid < NSTEP) {
        float spmax = log1pf(expf(bmax[0]));
        float spmin = log1pf(expf(bmin[0]));
        float a_ = spmax - spmin;
        float c_ = spmin;
        const float PI_ = 3.14159265358979323846f;
        float k = (float)tid;
        float t0 = k * DT_F, t1 = (k + 1.0f) * DT_F;
        float inv2pi = 1.0f / (2.0f * PI_);
        float F0 = a_ * sinf(PI_ * t0) * inv2pi + (0.5f * a_ + c_) * t0;
        float F1 = a_ * sinf(PI_ * t1) * inv2pi + (0.5f * a_ + c_) * t1;
        float al = 1.0f - expf(-2.0f * (F1 - F0));
        float gg = 1.0f - sqrtf(1.0f - al);
        float kap = (gg * gg) / al;
        tT[tid] = t0; tG[tid] = gg; tSd[tid] = sqrtf(al);
        tCd[tid] = -2.0f * kap; tCs[tid] = -2.0f * sqrtf(kap);
    }
    if (tid < HIDDEN) w1ts[tid] = W1[(size_t)192 * HIDDEN + tid];

    const bool isS = (wave < 8);
    const int zt  = wave & 3;            // S: z-quarter
    const int smt = (wave >> 2) & 1;     // S: m-tile
    const int q   = wave & 7;            // M: wave id 0..7

    bf16x8 W[16];                        // S: w2f[16]; M: w1f in W[0..7]
    f32x4  P[8];                         // M: pref[j2][mtt]; S: unused

    const int srow = smt * 16 + l16;     // S: my row (0..31)
    const int sz   = zt * 16 + g4 * 4;   // S: my z base
    const size_t sbase = (size_t)(row0 + srow);
    const int sswz = (srow & 7) << 3;
    float xs0 = 0.f, xs1 = 0.f, xs2 = 0.f, xs3 = 0.f, lwacc = 0.f;
    f32x4 b2f = { 0.f, 0.f, 0.f, 0.f };

    if (isS) {
        // ---- x state init + x_t[:,0,:] + Xb ----
        f32x4 xv = *(const f32x4*)(x0 + sbase * ZD + sz);
        *(f32x4*)(out + sbase * OUT_PITCH + sz) = xv;
        s16x4 xb4;
        xb4[0] = f2bs(xv[0]); xb4[1] = f2bs(xv[1]);
        xb4[2] = f2bs(xv[2]); xb4[3] = f2bs(xv[3]);
        *(s16x4*)(Xb + ((srow * 64 + sz) ^ sswz)) = xb4;
        xs0 = xv[0]; xs1 = xv[1]; xs2 = xv[2]; xs3 = xv[3];
        b2f = *(const f32x4*)(b2 + sz);
        // ---- w2f: A[n=z][k] = W2[k][z], full K=512 ----
        int n = zt * 16 + l16;
        #pragma unroll
        for (int kc = 0; kc < 16; ++kc) {
            bf16x8 v;
            #pragma unroll
            for (int j = 0; j < 8; ++j)
                v[j] = (__bf16)W2[(size_t)(kc * 32 + g4 * 8 + j) * ZD + n];
            W[kc] = v;
        }
    } else {
        // ---- pre-fragments via MFMA: P[j2*2+mtt] = b1 + r @ W1r ----
        #pragma unroll
        for (int mtt = 0; mtt < 2; ++mtt) {
            bf16x8 rf[4];
            const float* rp = r + (size_t)(row0 + mtt * 16 + l16) * RD;
            #pragma unroll
            for (int kc = 0; kc < 4; ++kc) {
                f32x4 lo = *(const f32x4*)(rp + kc * 32 + g4 * 8);
                f32x4 hi = *(const f32x4*)(rp + kc * 32 + g4 * 8 + 4);
                bf16x8 v;
                v[0]=(__bf16)lo[0]; v[1]=(__bf16)lo[1]; v[2]=(__bf16)lo[2]; v[3]=(__bf16)lo[3];
                v[4]=(__bf16)hi[0]; v[5]=(__bf16)hi[1]; v[6]=(__bf16)hi[2]; v[7]=(__bf16)hi[3];
                rf[kc] = v;
            }
            #pragma unroll
            for (int j2 = 0; j2 < 4; ++j2) {
                int n  = (q * 4 + j2) * 16 + l16;
                int n0 = (q * 4 + j2) * 16 + g4 * 4;
                f32x4 acc = *(const f32x4*)(b1 + n0);
                #pragma unroll
                for (int kc = 0; kc < 4; ++kc) {
                    bf16x8 w;
                    #pragma unroll
                    for (int j = 0; j < 8; ++j)
                        w[j] = (__bf16)W1[(size_t)(64 + kc * 32 + g4 * 8 + j) * HIDDEN + n];
                    acc = __builtin_amdgcn_mfma_f32_16x16x32_bf16(w, rf[kc], acc, 0, 0, 0);
                }
                P[j2 * 2 + mtt] = acc;
            }
        }
        // ---- w1f into W[0..7]: A[n][k] = W1[k][n] ----
        #pragma unroll
        for (int j2 = 0; j2 < 4; ++j2) {
            int n = (q * 4 + j2) * 16 + l16;
            #pragma unroll
            for (int kc = 0; kc < 2; ++kc) {
                bf16x8 v;
                #pragma unroll
                for (int j = 0; j < 8; ++j)
                    v[j] = (__bf16)W1[(size_t)(kc * 32 + g4 * 8 + j) * HIDDEN + n];
                W[j2 * 2 + kc] = v;
            }
        }
    }

    __syncthreads();

    f32x4 nz = { 0.f, 0.f, 0.f, 0.f };
    for (int s = 0; s < NSTEP; ++s) {
        if (!isS) {
            // ============ GEMM1: h = tanh(x@W1x + pre + t*w1t) -> Hs =======
            float t = tT[s];
            s16x8 xb[2][2];
            #pragma unroll
            for (int mtt = 0; mtt < 2; ++mtt) {
                int m = mtt * 16 + l16;
                int swz = (m & 7) << 3;
                xb[mtt][0] = *(const s16x8*)(Xb + ((m * 64 + g4 * 8) ^ swz));
                xb[mtt][1] = *(const s16x8*)(Xb + ((m * 64 + 32 + g4 * 8) ^ swz));
            }
            #pragma unroll
            for (int j2 = 0; j2 < 4; ++j2) {
                int n0 = (q * 4 + j2) * 16 + g4 * 4;
                f32x4 wt = *(const f32x4*)(w1ts + n0);
                #pragma unroll
                for (int mtt = 0; mtt < 2; ++mtt) {
                    f32x4 acc = P[j2 * 2 + mtt];
                    acc[0] = fmaf(t, wt[0], acc[0]);
                    acc[1] = fmaf(t, wt[1], acc[1]);
                    acc[2] = fmaf(t, wt[2], acc[2]);
                    acc[3] = fmaf(t, wt[3], acc[3]);
                    acc = __builtin_amdgcn_mfma_f32_16x16x32_bf16(
                        W[j2 * 2 + 0], __builtin_bit_cast(bf16x8, xb[mtt][0]), acc, 0, 0, 0);
                    acc = __builtin_amdgcn_mfma_f32_16x16x32_bf16(
                        W[j2 * 2 + 1], __builtin_bit_cast(bf16x8, xb[mtt][1]), acc, 0, 0, 0);
                    s16x4 hv;
                    hv[0] = f2bs(tanh_fast(acc[0]));
                    hv[1] = f2bs(tanh_fast(acc[1]));
                    hv[2] = f2bs(tanh_fast(acc[2]));
                    hv[3] = f2bs(tanh_fast(acc[3]));
                    int m = mtt * 16 + l16;
                    *(s16x4*)(Hs + ((m * HIDDEN + n0) ^ ((m & 7) << 3))) = hv;
                }
            }
        } else {
            // noise prefetch (consumed next phase; hidden under G1)
            nz = *(const f32x4*)(noises + (sbase * NSTEP + s) * ZD + sz);
        }
        __syncthreads();

        if (isS) {
            // ============ GEMM2 (full K) + update, one phase ===============
            f32x4 a0 = {0,0,0,0}, a1 = {0,0,0,0}, a2 = {0,0,0,0}, a3 = {0,0,0,0};
            int base = srow * HIDDEN + g4 * 8;
            #pragma unroll
            for (int kc = 0; kc < 16; kc += 4) {
                s16x8 h0 = *(const s16x8*)(Hs + ((base + kc * 32) ^ sswz));
                a0 = __builtin_amdgcn_mfma_f32_16x16x32_bf16(
                    W[kc], __builtin_bit_cast(bf16x8, h0), a0, 0, 0, 0);
                s16x8 h1 = *(const s16x8*)(Hs + ((base + (kc + 1) * 32) ^ sswz));
                a1 = __builtin_amdgcn_mfma_f32_16x16x32_bf16(
                    W[kc + 1], __builtin_bit_cast(bf16x8, h1), a1, 0, 0, 0);
                s16x8 h2 = *(const s16x8*)(Hs + ((base + (kc + 2) * 32) ^ sswz));
                a2 = __builtin_amdgcn_mfma_f32_16x16x32_bf16(
                    W[kc + 2], __builtin_bit_cast(bf16x8, h2), a2, 0, 0, 0);
                s16x8 h3 = *(const s16x8*)(Hs + ((base + (kc + 3) * 32) ^ sswz));
                a3 = __builtin_amdgcn_mfma_f32_16x16x32_bf16(
                    W[kc + 3], __builtin_bit_cast(bf16x8, h3), a3, 0, 0, 0);
            }
            float gg = tG[s], sdv = tSd[s], cd = tCd[s], cs = tCs[s];
            f32x4 sc;
            sc[0] = ((a0[0] + a1[0]) + (a2[0] + a3[0])) + b2f[0];
            sc[1] = ((a0[1] + a1[1]) + (a2[1] + a3[1])) + b2f[1];
            sc[2] = ((a0[2] + a1[2]) + (a2[2] + a3[2])) + b2f[2];
            sc[3] = ((a0[3] + a1[3]) + (a2[3] + a3[3])) + b2f[3];
            float xn0 = xs0 + gg * (2.0f * sc[0] - xs0) + sdv * nz[0];
            float xn1 = xs1 + gg * (2.0f * sc[1] - xs1) + sdv * nz[1];
            float xn2 = xs2 + gg * (2.0f * sc[2] - xs2) + sdv * nz[2];
            float xn3 = xs3 + gg * (2.0f * sc[3] - xs3) + sdv * nz[3];
            f32x4 xv = { xn0, xn1, xn2, xn3 };
            *(f32x4*)(out + sbase * OUT_PITCH + (size_t)(s + 1) * ZD + sz) = xv;
            s16x4 xb4;
            xb4[0] = f2bs(xn0); xb4[1] = f2bs(xn1);
            xb4[2] = f2bs(xn2); xb4[3] = f2bs(xn3);
            *(s16x4*)(Xb + ((srow * 64 + sz) ^ sswz)) = xb4;
            float pd = sc[0]*sc[0] + sc[1]*sc[1] + sc[2]*sc[2] + sc[3]*sc[3];
            float ps = sc[0]*nz[0] + sc[1]*nz[1] + sc[2]*nz[2] + sc[3]*nz[3];
            lwacc += cd * pd + cs * ps;
            xs0 = xn0; xs1 = xn1; xs2 = xn2; xs3 = xn3;
        }
        __syncthreads();
    }

    // ---- finalize: log_weights and nabla_g ----
    if (isS) {
        f32x4 mv = *(const f32x4*)(mu + sz);
        float d0 = xs0 - mv[0], d1 = xs1 - mv[1];
        float d2 = xs2 - mv[2], d3 = xs3 - mv[3];
        f32x4 ng = { d0 - xs0, d1 - xs1, d2 - xs2, d3 - xs3 };   // == -mu
        *(f32x4*)(out + NG_OFF + sbase * ZD + sz) = ng;
        float tp = 0.5f * (xs0*xs0 + xs1*xs1 + xs2*xs2 + xs3*xs3)
                 - 0.5f * (d0*d0 + d1*d1 + d2*d2 + d3*d3);
        float v = lwacc + tp;
        v += __shfl_xor(v, 16, 64);
        v += __shfl_xor(v, 32, 64);
        if (g4 == 0) lwP[zt][srow] = v;
    }
    __syncthreads();
    if (tid < ROWS) {
        out[LW_OFF + row0 + tid] =
            lwP[0][tid] + lwP[1][tid] + lwP[2][tid] + lwP[3][tid];
    }
}

extern "C" void kernel_launch(void* const* d_in, const int* in_sizes, int n_in,
                              void* d_out, int out_size, void* d_ws, size_t ws_size,
                              hipStream_t stream) {
    const float* r      = (const float*)d_in[0];
    const float* noises = (const float*)d_in[1];
    const float* x0     = (const float*)d_in[2];
    const float* W1     = (const float*)d_in[3];
    const float* b1     = (const float*)d_in[4];
    const float* W2     = (const float*)d_in[5];
    const float* b2     = (const float*)d_in[6];
    const float* bmax   = (const float*)d_in[7];
    const float* bmin   = (const float*)d_in[8];
    const float* mu     = (const float*)d_in[9];
    float* out = (float*)d_out;

    sim_kernel<<<256, 1024, 0, stream>>>(r, noises, x0, W1, b1, W2, b2,
                                         bmax, bmin, mu, out);
}

// Round 8
// 241.164 us; speedup vs baseline: 2.2813x; 2.2813x over previous
//
#include <hip/hip_runtime.h>

#define ZD 64
#define RD 128
#define HIDDEN 512
#define NSTEP 100
#define OUT_PITCH 6464              // 101*64
#define DT_F 0.01f
#define ROWS 32

static const size_t LW_OFF = 52953088ull;   // 8192*101*64
static const size_t NG_OFF = 52961280ull;   // + 8192

typedef __attribute__((ext_vector_type(2))) float  f32x2;
typedef __attribute__((ext_vector_type(4))) float  f32x4;
typedef __attribute__((ext_vector_type(8))) __bf16 bf16x8;
typedef __attribute__((ext_vector_type(2))) short  s16x2;
typedef __attribute__((ext_vector_type(4))) short  s16x4;
typedef __attribute__((ext_vector_type(8))) short  s16x8;

__device__ __forceinline__ short f2bs(float f) {
    return __builtin_bit_cast(short, (__bf16)f);
}
__device__ __forceinline__ float tanh_fast(float x) {
    float e = __builtin_amdgcn_exp2f(x * 2.88539008177793f);
    float r = __builtin_amdgcn_rcpf(e + 1.0f);
    return fmaf(-2.0f, r, 1.0f);
}

// ---------------------------------------------------------------------------
// sim_kernel: persistent scan. 256 blocks x 1024 threads (16 waves), 32 rows,
// 1 block/CU. Combined VGPR+AGPR pinned at 128/wave (R6 proven shape).
// DS-traffic-reduced vs R6:
//   GEMM2 roles (z-half x K-quarter x m-tile): each h ds_read feeds 2 MFMAs
//     -> 4 reads/thread (was 8). Ps[4] partials, row stride 72 (4-way max).
//   lw reduction deferred out of the step loop (per-thread scalar acc).
//   b2 in registers (no per-step LDS read).
// ---------------------------------------------------------------------------
__global__ __launch_bounds__(1024, 1)
void sim_kernel(
    const float* __restrict__ r, const float* __restrict__ noises,
    const float* __restrict__ x0, const float* __restrict__ W1,
    const float* __restrict__ b1, const float* __restrict__ W2,
    const float* __restrict__ b2, const float* __restrict__ bmax,
    const float* __restrict__ bmin, const float* __restrict__ mu,
    float* __restrict__ out)
{
    __shared__ float Ps[4][ROWS][72];                 // 36864 B
    __shared__ unsigned short Xb[ROWS * 64];          // 4096 B
    __shared__ unsigned short Hs[ROWS * HIDDEN];      // 32768 B
    __shared__ float w1ts[HIDDEN];                    // 2048 B
    __shared__ float tT[NSTEP], tG[NSTEP], tSd[NSTEP], tCd[NSTEP], tCs[NSTEP]; // 2000 B

    const int tid  = threadIdx.x;
    const int lane = tid & 63;
    const int wave = tid >> 6;       // 0..15
    const int g4   = lane >> 4;      // 0..3
    const int l16  = lane & 15;
    const int row0 = blockIdx.x * ROWS;

    // ---- step tables ----
    if (tid < NSTEP) {
        float spmax = log1pf(expf(bmax[0]));
        float spmin = log1pf(expf(bmin[0]));
        float a_ = spmax - spmin;
        float c_ = spmin;
        const float PI_ = 3.14159265358979323846f;
        float k = (float)tid;
        float t0 = k * DT_F, t1 = (k + 1.0f) * DT_F;
        float inv2pi = 1.0f / (2.0f * PI_);
        float F0 = a_ * sinf(PI_ * t0) * inv2pi + (0.5f * a_ + c_) * t0;
        float F1 = a_ * sinf(PI_ * t1) * inv2pi + (0.5f * a_ + c_) * t1;
        float al = 1.0f - expf(-2.0f * (F1 - F0));
        float gg = 1.0f - sqrtf(1.0f - al);
        float kap = (gg * gg) / al;
        tT[tid] = t0; tG[tid] = gg; tSd[tid] = sqrtf(al);
        tCd[tid] = -2.0f * kap; tCs[tid] = -2.0f * sqrtf(kap);
    }
    if (tid < HIDDEN) w1ts[tid] = W1[(size_t)192 * HIDDEN + tid];

    // ---- x state init (update-thread registers) + x_t[:,0,:] + Xb ----
    const int urow = tid >> 5;          // 0..31
    const int c2   = (tid & 31) * 2;    // 0..62
    const size_t ubase = (size_t)(row0 + urow);
    float xr0, xr1;
    {
        f32x2 v = *(const f32x2*)(x0 + ubase * ZD + c2);
        xr0 = v[0]; xr1 = v[1];
        *(f32x2*)(out + ubase * OUT_PITCH + c2) = v;
        s16x2 xv; xv[0] = f2bs(xr0); xv[1] = f2bs(xr1);
        *(s16x2*)(Xb + ((urow * 64 + c2) ^ ((urow & 7) << 3))) = xv;
    }
    const float bb0 = b2[c2], bb1 = b2[c2 + 1];

    // ---- pre-fragments via MFMA: pref[j2][mt] = b1 + r @ W1r ----
    f32x4 pref[2][2];
    {
        #pragma unroll
        for (int mtt = 0; mtt < 2; ++mtt) {
            bf16x8 rf[4];
            const float* rp = r + (size_t)(row0 + mtt * 16 + l16) * RD;
            #pragma unroll
            for (int kc = 0; kc < 4; ++kc) {
                f32x4 lo = *(const f32x4*)(rp + kc * 32 + g4 * 8);
                f32x4 hi = *(const f32x4*)(rp + kc * 32 + g4 * 8 + 4);
                bf16x8 v;
                v[0]=(__bf16)lo[0]; v[1]=(__bf16)lo[1]; v[2]=(__bf16)lo[2]; v[3]=(__bf16)lo[3];
                v[4]=(__bf16)hi[0]; v[5]=(__bf16)hi[1]; v[6]=(__bf16)hi[2]; v[7]=(__bf16)hi[3];
                rf[kc] = v;
            }
            #pragma unroll
            for (int j2 = 0; j2 < 2; ++j2) {
                int n  = (wave * 2 + j2) * 16 + l16;
                int n0 = (wave * 2 + j2) * 16 + g4 * 4;
                f32x4 acc = *(const f32x4*)(b1 + n0);
                #pragma unroll
                for (int kc = 0; kc < 4; ++kc) {
                    bf16x8 w;
                    #pragma unroll
                    for (int j = 0; j < 8; ++j)
                        w[j] = (__bf16)W1[(size_t)(64 + kc * 32 + g4 * 8 + j) * HIDDEN + n];
                    acc = __builtin_amdgcn_mfma_f32_16x16x32_bf16(w, rf[kc], acc, 0, 0, 0);
                }
                pref[j2][mtt] = acc;
            }
        }
    }

    // ---- persistent weight fragments ----
    bf16x8 w1f[2][2];                // [j2][kc]
    #pragma unroll
    for (int j2 = 0; j2 < 2; ++j2) {
        int n = (wave * 2 + j2) * 16 + l16;
        #pragma unroll
        for (int kc = 0; kc < 2; ++kc) {
            bf16x8 v;
            #pragma unroll
            for (int j = 0; j < 8; ++j) {
                int kk = kc * 32 + g4 * 8 + j;
                v[j] = (__bf16)W1[(size_t)kk * HIDDEN + n];
            }
            w1f[j2][kc] = v;
        }
    }
    // GEMM2 roles: zh = wave&1 (z-half), kq = (wave>>1)&3 (K-quarter),
    //              mtw = wave>>3 (m-tile). Each h read feeds 2 z-tiles.
    const int zh = wave & 1, kq = (wave >> 1) & 3, mtw = wave >> 3;
    bf16x8 w2f[2][4];
    #pragma unroll
    for (int zt2 = 0; zt2 < 2; ++zt2) {
        int n = (zh * 2 + zt2) * 16 + l16;
        #pragma unroll
        for (int i = 0; i < 4; ++i) {
            bf16x8 v;
            #pragma unroll
            for (int j = 0; j < 8; ++j)
                v[j] = (__bf16)W2[(size_t)(kq * 128 + i * 32 + g4 * 8 + j) * ZD + n];
            w2f[zt2][i] = v;
        }
    }

    float lwacc = 0.0f;

    __syncthreads();

    for (int s = 0; s < NSTEP; ++s) {
        float t = tT[s];
        // noise prefetch for update phase (hidden under 2 barriers)
        f32x2 nz = *(const f32x2*)(noises + (ubase * NSTEP + s) * ZD + c2);

        // ================= GEMM1: h = tanh(x@W1x + pre + t*w1t) ============
        {
            s16x8 xb[2][2];
            #pragma unroll
            for (int mtt = 0; mtt < 2; ++mtt) {
                int m = mtt * 16 + l16;
                int swz = (m & 7) << 3;
                xb[mtt][0] = *(const s16x8*)(Xb + ((m * 64 + g4 * 8) ^ swz));
                xb[mtt][1] = *(const s16x8*)(Xb + ((m * 64 + 32 + g4 * 8) ^ swz));
            }
            #pragma unroll
            for (int j2 = 0; j2 < 2; ++j2) {
                int n0 = (wave * 2 + j2) * 16 + g4 * 4;
                f32x4 wt = *(const f32x4*)(w1ts + n0);
                #pragma unroll
                for (int mtt = 0; mtt < 2; ++mtt) {
                    f32x4 acc = pref[j2][mtt];
                    acc[0] = fmaf(t, wt[0], acc[0]);
                    acc[1] = fmaf(t, wt[1], acc[1]);
                    acc[2] = fmaf(t, wt[2], acc[2]);
                    acc[3] = fmaf(t, wt[3], acc[3]);
                    acc = __builtin_amdgcn_mfma_f32_16x16x32_bf16(
                        w1f[j2][0], __builtin_bit_cast(bf16x8, xb[mtt][0]), acc, 0, 0, 0);
                    acc = __builtin_amdgcn_mfma_f32_16x16x32_bf16(
                        w1f[j2][1], __builtin_bit_cast(bf16x8, xb[mtt][1]), acc, 0, 0, 0);
                    s16x4 hv;
                    hv[0] = f2bs(tanh_fast(acc[0]));
                    hv[1] = f2bs(tanh_fast(acc[1]));
                    hv[2] = f2bs(tanh_fast(acc[2]));
                    hv[3] = f2bs(tanh_fast(acc[3]));
                    int m = mtt * 16 + l16;
                    *(s16x4*)(Hs + ((m * HIDDEN + n0) ^ ((m & 7) << 3))) = hv;
                }
            }
        }
        __syncthreads();

        // ====== GEMM2 (z-half x K-quarter x m-tile): partials -> Ps[kq] ====
        {
            int m = mtw * 16 + l16;
            int swz = (m & 7) << 3;
            int base = m * HIDDEN + kq * 128 + g4 * 8;
            f32x4 aA = { 0.f, 0.f, 0.f, 0.f };
            f32x4 aB = { 0.f, 0.f, 0.f, 0.f };
            #pragma unroll
            for (int i = 0; i < 4; ++i) {
                s16x8 h = *(const s16x8*)(Hs + ((base + i * 32) ^ swz));
                aA = __builtin_amdgcn_mfma_f32_16x16x32_bf16(
                    w2f[0][i], __builtin_bit_cast(bf16x8, h), aA, 0, 0, 0);
                aB = __builtin_amdgcn_mfma_f32_16x16x32_bf16(
                    w2f[1][i], __builtin_bit_cast(bf16x8, h), aB, 0, 0, 0);
            }
            *(f32x4*)(&Ps[kq][m][(zh * 2 + 0) * 16 + g4 * 4]) = aA;
            *(f32x4*)(&Ps[kq][m][(zh * 2 + 1) * 16 + g4 * 4]) = aB;
        }
        __syncthreads();

        // ================= Update (x in registers, lw deferred) ============
        {
            float gg = tG[s], sdv = tSd[s], cd = tCd[s], cs = tCs[s];
            f32x2 p0 = *(const f32x2*)(&Ps[0][urow][c2]);
            f32x2 p1 = *(const f32x2*)(&Ps[1][urow][c2]);
            f32x2 p2 = *(const f32x2*)(&Ps[2][urow][c2]);
            f32x2 p3 = *(const f32x2*)(&Ps[3][urow][c2]);
            float s0 = ((p0[0] + p1[0]) + (p2[0] + p3[0])) + bb0;
            float s1 = ((p0[1] + p1[1]) + (p2[1] + p3[1])) + bb1;
            float xn0 = xr0 + gg * (2.0f * s0 - xr0) + sdv * nz[0];
            float xn1 = xr1 + gg * (2.0f * s1 - xr1) + sdv * nz[1];
            xr0 = xn0; xr1 = xn1;
            f32x2 xv = { xn0, xn1 };
            *(f32x2*)(out + ubase * OUT_PITCH + (size_t)(s + 1) * ZD + c2) = xv;
            s16x2 xb2; xb2[0] = f2bs(xn0); xb2[1] = f2bs(xn1);
            *(s16x2*)(Xb + ((urow * 64 + c2) ^ ((urow & 7) << 3))) = xb2;
            lwacc += cd * (s0 * s0 + s1 * s1) + cs * (s0 * nz[0] + s1 * nz[1]);
        }
        __syncthreads();
    }

    // ---- finalize: log_weights and nabla_g ----
    {
        float m0 = mu[c2], m1 = mu[c2 + 1];
        float d0 = xr0 - m0, d1 = xr1 - m1;
        f32x2 ng = { d0 - xr0, d1 - xr1 };           // == -mu
        *(f32x2*)(out + NG_OFF + ubase * ZD + c2) = ng;
        float part = lwacc
                   + 0.5f * (xr0 * xr0 + xr1 * xr1) - 0.5f * (d0 * d0 + d1 * d1);
        part += __shfl_xor(part, 1, 64);
        part += __shfl_xor(part, 2, 64);
        part += __shfl_xor(part, 4, 64);
        part += __shfl_xor(part, 8, 64);
        part += __shfl_xor(part, 16, 64);
        if ((tid & 31) == 0) out[LW_OFF + ubase] = part;
    }
}

extern "C" void kernel_launch(void* const* d_in, const int* in_sizes, int n_in,
                              void* d_out, int out_size, void* d_ws, size_t ws_size,
                              hipStream_t stream) {
    const float* r      = (const float*)d_in[0];
    const float* noises = (const float*)d_in[1];
    const float* x0     = (const float*)d_in[2];
    const float* W1     = (const float*)d_in[3];
    const float* b1     = (const float*)d_in[4];
    const float* W2     = (const float*)d_in[5];
    const float* b2     = (const float*)d_in[6];
    const float* bmax   = (const float*)d_in[7];
    const float* bmin   = (const float*)d_in[8];
    const float* mu     = (const float*)d_in[9];
    float* out = (float*)d_out;

    sim_kernel<<<256, 1024, 0, stream>>>(r, noises, x0, W1, b1, W2, b2,
                                         bmax, bmin, mu, out);
}